// Round 6
// baseline (390.338 us; speedup 1.0000x reference)
//
#include <hip/hip_runtime.h>
#include <hip/hip_fp16.h>

#define N_NODES 100000
#define N_EDGES 1600000
#define D 32
#define D2 16   // half2 per row
#define ROWS_PER_BLOCK 64
#define XS_STRIDE 36  // 32 + 4 floats: 16B-aligned, breaks bank aliasing
#define NTILES ((N_NODES + ROWS_PER_BLOCK - 1) / ROWS_PER_BLOCK)  // 1563
#define YH_ELEMS (N_NODES * D)   // halves
#define AGG_F4 (YH_ELEMS / 8)    // float4 covering agg_h
#define NBLK 1024                // 4 blocks/CU * 256 CUs -> guaranteed co-resident

union Half8 {
    __half2 h2[4];
    float4 f4;
};

struct Bar {
    int cnt; int pad0[15];
    int flag; int pad1[15];
};  // 128 B

__device__ __forceinline__ void grid_barrier(Bar* b, int nblk) {
    __syncthreads();  // emits s_waitcnt vmcnt(0) first: block's stores/atomics retired
    if (threadIdx.x == 0) {
        // ACQ_REL @ AGENT: release side writes back this XCD's L2 to the LLC
        int v = __hip_atomic_fetch_add(&b->cnt, 1, __ATOMIC_ACQ_REL, __HIP_MEMORY_SCOPE_AGENT);
        if (v == nblk - 1) {
            __hip_atomic_store(&b->flag, 1, __ATOMIC_RELEASE, __HIP_MEMORY_SCOPE_AGENT);
        } else {
            while (__hip_atomic_load(&b->flag, __ATOMIC_ACQUIRE, __HIP_MEMORY_SCOPE_AGENT) == 0)
                __builtin_amdgcn_s_sleep(8);
        }
    }
    __syncthreads();
}

// One persistent kernel: phase1 linear(+zero agg) | barrier | phase2 scatter |
// barrier | phase3 convert. 1024 blocks x 256 thr; launch_bounds(256,4) caps
// VGPR at 128 so 4 blocks/CU residency (the barrier's safety condition) holds.
__global__ __launch_bounds__(256, 4) void gcn_fused_kernel(
    const float* __restrict__ x,
    const int* __restrict__ edge_index,
    const float* __restrict__ W,
    float* __restrict__ out,
    __half* __restrict__ y_h,
    __half2* __restrict__ agg2,
    Bar* bars) {
    __shared__ float xs[ROWS_PER_BLOCK * XS_STRIDE];  // 9216 B
    __shared__ float Wt[D * D];                       // Wt[k*32+o] = W[o*32+k]
    int t = threadIdx.x;
    const int nthreads = NBLK * 256;
    int gtid = blockIdx.x * 256 + t;

    // ---- phase 1a: zero agg_h (grid-stride) + stage Wt
    float4* aggz = (float4*)agg2;
    for (int i = gtid; i < AGG_F4; i += nthreads)
        aggz[i] = make_float4(0.f, 0.f, 0.f, 0.f);
#pragma unroll
    for (int i = t; i < D * D; i += 256) {
        int o = i >> 5, k = i & 31;
        Wt[k * D + o] = W[i];
    }

    // ---- phase 1b: y_h = half(x @ W^T), 64-row tiles, grid-stride
    for (int tile = blockIdx.x; tile < NTILES; tile += NBLK) {
        int row0 = tile * ROWS_PER_BLOCK;
#pragma unroll
        for (int p = 0; p < 2; ++p) {
            int fi = p * 256 + t;
            int r = fi >> 3, c4 = fi & 7;
            int grow = row0 + r;
            if (grow < N_NODES)
                *(float4*)&xs[r * XS_STRIDE + c4 * 4] =
                    ((const float4*)(x + (size_t)grow * D))[c4];
        }
        __syncthreads();  // also covers Wt staging on first iteration
        int r = t >> 2, q = t & 3;
        int grow = row0 + r;
        if (grow < N_NODES) {
            float acc[8];
#pragma unroll
            for (int j = 0; j < 8; ++j) acc[j] = 0.f;
#pragma unroll
            for (int k = 0; k < D; ++k) {
                float v = xs[r * XS_STRIDE + k];
#pragma unroll
                for (int j = 0; j < 8; ++j) acc[j] += v * Wt[k * D + q * 8 + j];
            }
            Half8 hv;
#pragma unroll
            for (int j = 0; j < 4; ++j)
                hv.h2[j] = __floats2half2_rn(acc[2 * j], acc[2 * j + 1]);
            *(float4*)&y_h[(size_t)grow * D + q * 8] = hv.f4;
        }
        __syncthreads();
    }

    grid_barrier(&bars[0], NBLK);  // y_h + zeroed agg now LLC-visible

    // ---- phase 2: agg_h[dst[e],:] += y_h[src[e],:] (pk_add_f16 atomics @ LLC)
    {
        const int* src = edge_index;
        const int* dst = edge_index + N_EDGES;
        const __half2* y2 = (const __half2*)y_h;
        for (int g = gtid; g < N_EDGES * D2; g += nthreads) {
            int e = g >> 4, f2 = g & 15;
            int s = src[e], dd = dst[e];
            unsafeAtomicAdd(&agg2[(size_t)dd * D2 + f2], y2[(size_t)s * D2 + f2]);
        }
    }

    grid_barrier(&bars[1], NBLK);  // all atomics committed

    // ---- phase 3: out = float(agg_h)
    {
        const float4* agg4 = (const float4*)agg2;
        float4* out4 = (float4*)out;
        for (int i = gtid; i < AGG_F4; i += nthreads) {
            Half8 hv;
            hv.f4 = agg4[i];
            out4[2 * i] = make_float4(
                __half2float(__low2half(hv.h2[0])), __half2float(__high2half(hv.h2[0])),
                __half2float(__low2half(hv.h2[1])), __half2float(__high2half(hv.h2[1])));
            out4[2 * i + 1] = make_float4(
                __half2float(__low2half(hv.h2[2])), __half2float(__high2half(hv.h2[2])),
                __half2float(__low2half(hv.h2[3])), __half2float(__high2half(hv.h2[3])));
        }
    }
}

// ---------- fallback path (R5 structure) if ws is too small for barriers ----------
__global__ __launch_bounds__(256) void gcn_linear_kernel(
    const float* __restrict__ x, const float* __restrict__ W,
    __half* __restrict__ y_h, float4* __restrict__ agg_zero) {
    __shared__ float xs[ROWS_PER_BLOCK * XS_STRIDE];
    __shared__ float Wt[D * D];
    int t = threadIdx.x;
    int b = blockIdx.x;
    {
        int zi = b * 256 + t;
        if (zi < YH_ELEMS / 8) agg_zero[zi] = make_float4(0.f, 0.f, 0.f, 0.f);
    }
#pragma unroll
    for (int i = t; i < D * D; i += 256) {
        int o = i >> 5, k = i & 31;
        Wt[k * D + o] = W[i];
    }
    int row0 = b * ROWS_PER_BLOCK;
#pragma unroll
    for (int p = 0; p < 2; ++p) {
        int fi = p * 256 + t;
        int r = fi >> 3, c4 = fi & 7;
        int grow = row0 + r;
        if (grow < N_NODES)
            *(float4*)&xs[r * XS_STRIDE + c4 * 4] = ((const float4*)(x + (size_t)grow * D))[c4];
    }
    __syncthreads();
    int r = t >> 2, q = t & 3;
    int grow = row0 + r;
    if (grow >= N_NODES) return;
    float acc[8];
#pragma unroll
    for (int j = 0; j < 8; ++j) acc[j] = 0.f;
#pragma unroll
    for (int k = 0; k < D; ++k) {
        float v = xs[r * XS_STRIDE + k];
#pragma unroll
        for (int j = 0; j < 8; ++j) acc[j] += v * Wt[k * D + q * 8 + j];
    }
    Half8 hv;
#pragma unroll
    for (int j = 0; j < 4; ++j) hv.h2[j] = __floats2half2_rn(acc[2 * j], acc[2 * j + 1]);
    *(float4*)&y_h[(size_t)grow * D + q * 8] = hv.f4;
}

__global__ __launch_bounds__(256) void gcn_scatter_kernel(
    const int* __restrict__ src, const int* __restrict__ dst,
    const __half2* __restrict__ y2, __half2* __restrict__ agg2) {
    int gid = blockIdx.x * 256 + threadIdx.x;
    int e = gid >> 4, f2 = gid & 15;
    if (e >= N_EDGES) return;
    unsafeAtomicAdd(&agg2[(size_t)dst[e] * D2 + f2], y2[(size_t)src[e] * D2 + f2]);
}

__global__ __launch_bounds__(256) void convert_kernel(
    const float4* __restrict__ agg4, float4* __restrict__ out4) {
    int i = blockIdx.x * 256 + threadIdx.x;
    if (i >= YH_ELEMS / 8) return;
    Half8 hv;
    hv.f4 = agg4[i];
    out4[2 * i] = make_float4(
        __half2float(__low2half(hv.h2[0])), __half2float(__high2half(hv.h2[0])),
        __half2float(__low2half(hv.h2[1])), __half2float(__high2half(hv.h2[1])));
    out4[2 * i + 1] = make_float4(
        __half2float(__low2half(hv.h2[2])), __half2float(__high2half(hv.h2[2])),
        __half2float(__low2half(hv.h2[3])), __half2float(__high2half(hv.h2[3])));
}

extern "C" void kernel_launch(void* const* d_in, const int* in_sizes, int n_in,
                              void* d_out, int out_size, void* d_ws, size_t ws_size,
                              hipStream_t stream) {
    const float* x = (const float*)d_in[0];
    const int* edge_index = (const int*)d_in[1];  // [2, N_EDGES] int32
    const float* W = (const float*)d_in[2];
    float* out = (float*)d_out;

    __half* y_h = (__half*)d_ws;
    __half2* agg2 = (__half2*)((char*)d_ws + (size_t)YH_ELEMS * sizeof(__half));
    Bar* bars = (Bar*)((char*)d_ws + (size_t)YH_ELEMS * 2 * sizeof(__half));
    size_t need = (size_t)YH_ELEMS * 2 * sizeof(__half) + 2 * sizeof(Bar);

    if (ws_size >= need) {
        // single persistent kernel + tiny barrier memset
        hipMemsetAsync(bars, 0, 2 * sizeof(Bar), stream);
        gcn_fused_kernel<<<NBLK, 256, 0, stream>>>(x, edge_index, W, out, y_h, agg2, bars);
    } else {
        // proven R5 3-kernel path
        const int* src = edge_index;
        const int* dst = edge_index + N_EDGES;
        gcn_linear_kernel<<<NTILES, 256, 0, stream>>>(x, W, y_h, (float4*)agg2);
        int sc_blocks = (N_EDGES * D2 + 255) / 256;
        gcn_scatter_kernel<<<sc_blocks, 256, 0, stream>>>(src, dst, (const __half2*)y_h, agg2);
        int cv_blocks = (YH_ELEMS / 8 + 255) / 256;
        convert_kernel<<<cv_blocks, 256, 0, stream>>>((const float4*)agg2, (float4*)d_out);
    }
}